// Round 4
// baseline (322.744 us; speedup 1.0000x reference)
//
#include <hip/hip_runtime.h>
#include <hip/hip_bf16.h>
#include <stdint.h>

#define IN_F 4096
#define OUT_F 4096
#define NG 32

typedef __attribute__((ext_vector_type(8))) short short8;
typedef __attribute__((ext_vector_type(4))) float floatx4;

#define DQ_BLOCKS 8192   // dequant: 2097152 int32 / 256
#define CV_BLOCKS 2048   // convert: 1024*4096 floats / 8 / 256

// Fused prep: blocks [0, DQ_BLOCKS) dequant W, [DQ_BLOCKS, +CV_BLOCKS) convert x.
__global__ __launch_bounds__(256) void prep_kernel(
    const int* __restrict__ wp, const float* __restrict__ scale,
    const int* __restrict__ zero, __hip_bfloat16* __restrict__ Wb,
    const float* __restrict__ x, __hip_bfloat16* __restrict__ xb) {
  int b = blockIdx.x;
  if (b < DQ_BLOCKS) {
    int p = b * 256 + threadIdx.x;                  // 0 .. 2097151
    int row = p >> 9;                               // 512 int32 per output row
    int g = (p >> 4) & 31;                          // 16 int32 per 128-group
    float s = scale[row * NG + g];
    float zs = (float)zero[row * NG + g] * s;
    unsigned v = (unsigned)wp[p];
    union { __hip_bfloat16 h[8]; uint4 u4; } o;
#pragma unroll
    for (int i = 0; i < 8; ++i) {
      int q = (int)((v >> (4 * i)) & 15u);
      q -= (q >= 8) ? 16 : 0;                       // signed 4-bit
      o.h[i] = __float2bfloat16((float)q * s - zs); // (q - zero) * scale
    }
    *(uint4*)(Wb + (size_t)p * 8) = o.u4;
  } else {
    int i = (b - DQ_BLOCKS) * 256 + threadIdx.x;    // 8 floats per thread
    float4 v0 = ((const float4*)x)[i * 2];
    float4 v1 = ((const float4*)x)[i * 2 + 1];
    union { __hip_bfloat16 h[8]; uint4 u4; } o;
    o.h[0] = __float2bfloat16(v0.x); o.h[1] = __float2bfloat16(v0.y);
    o.h[2] = __float2bfloat16(v0.z); o.h[3] = __float2bfloat16(v0.w);
    o.h[4] = __float2bfloat16(v1.x); o.h[5] = __float2bfloat16(v1.y);
    o.h[6] = __float2bfloat16(v1.z); o.h[7] = __float2bfloat16(v1.w);
    ((uint4*)xb)[i] = o.u4;
  }
}

// C[m][n] = sum_k A[m][k] * Bt[n][k]; split-K over blockIdx.z (SK = gridDim.z).
// Each z writes a compact per-tile partial slab (coalesced float4); last z to
// arrive (device-scope counter) sums all slabs and writes C. No per-elem atomics.
#define BM 128
#define BN 128
#define BK 64

__global__ __launch_bounds__(256) void gemm_bt(
    const __hip_bfloat16* __restrict__ A, const __hip_bfloat16* __restrict__ Bt,
    float* __restrict__ C, float* __restrict__ Parts, unsigned* __restrict__ cnt,
    int M, int N, int K) {
  __shared__ short Alds[BM * BK];   // [row][k], stride 64, unpadded (global_load_lds)
  __shared__ short Blds[BN * BK];
  __shared__ int lastFlag;

  int t = threadIdx.x;
  int wave = t >> 6, lane = t & 63;
  int wm = (wave >> 1) * 64, wn = (wave & 1) * 64;
  int r = lane & 15, quad = lane >> 4;
  int bm = blockIdx.y * BM, bn = blockIdx.x * BN;
  int SK = gridDim.z;
  int kchunk = K / SK;
  int kz = blockIdx.z * kchunk;
  int kend = kz + kchunk;
  int tile = blockIdx.y * gridDim.x + blockIdx.x;   // 0..255

  floatx4 acc[4][4] = {};

  const __hip_bfloat16* Ag = A + (size_t)bm * K;
  const __hip_bfloat16* Bg = Bt + (size_t)bn * K;

  for (int k0 = kz; k0 < kend; k0 += BK) {
    __syncthreads();  // previous compute done before overwriting LDS
#pragma unroll
    for (int j = 0; j < 4; ++j) {
      int c = t + 256 * j;            // 16B chunk id, 8 chunks per row
      int row = c >> 3, kc = c & 7;
      const __hip_bfloat16* ga = Ag + (size_t)row * K + k0 + kc * 8;
      const __hip_bfloat16* gb = Bg + (size_t)row * K + k0 + kc * 8;
      __builtin_amdgcn_global_load_lds(
          (const __attribute__((address_space(1))) void*)ga,
          (__attribute__((address_space(3))) void*)(&Alds[c * 8]), 16, 0, 0);
      __builtin_amdgcn_global_load_lds(
          (const __attribute__((address_space(1))) void*)gb,
          (__attribute__((address_space(3))) void*)(&Blds[c * 8]), 16, 0, 0);
    }
    __syncthreads();  // implies vmcnt(0): staged data visible

#pragma unroll
    for (int ks = 0; ks < 2; ++ks) {
      int kk = ks * 32;
      short8 af[4], bf[4];
#pragma unroll
      for (int mi = 0; mi < 4; ++mi)
        af[mi] = *(const short8*)&Alds[(wm + mi * 16 + r) * BK + kk + quad * 8];
#pragma unroll
      for (int ni = 0; ni < 4; ++ni)
        bf[ni] = *(const short8*)&Blds[(wn + ni * 16 + r) * BK + kk + quad * 8];
#pragma unroll
      for (int mi = 0; mi < 4; ++mi)
#pragma unroll
        for (int ni = 0; ni < 4; ++ni)
          acc[mi][ni] = __builtin_amdgcn_mfma_f32_16x16x32_bf16(
              af[mi], bf[ni], acc[mi][ni], 0, 0, 0);
    }
  }

  // --- Write compact partial slab: perfectly coalesced float4 stores. ---
  // Slab layout: chunk c = mi*4+ni in [0,16); offset c*1024 + t*4 floats.
  float* slab = Parts + ((size_t)tile * SK + blockIdx.z) * (BM * BN);
#pragma unroll
  for (int mi = 0; mi < 4; ++mi)
#pragma unroll
    for (int ni = 0; ni < 4; ++ni)
      *(floatx4*)&slab[(mi * 4 + ni) * 1024 + t * 4] = acc[mi][ni];

  __threadfence();      // release: partial stores device-visible before count
  __syncthreads();      // all threads' fences before the counter bump
  if (t == 0) {
    unsigned old = atomicAdd(&cnt[tile], 1u);      // device-scope
    lastFlag = (old == (unsigned)(SK - 1)) ? 1 : 0;
  }
  __syncthreads();
  if (!lastFlag) return;

  // --- Last block for this tile: acquire, sum all slabs, write C. ---
  __threadfence();      // acquire: invalidate stale lines (cross-XCD / poison)
  const float* base = Parts + (size_t)tile * SK * (BM * BN);
#pragma unroll
  for (int c = 0; c < 16; ++c) {
    float sx = 0.f, sy = 0.f, sz = 0.f, sw = 0.f;
    for (int z = 0; z < SK; ++z) {
      const floatx4 v = *(const floatx4*)&base[(size_t)z * (BM * BN) + c * 1024 + t * 4];
      sx += v[0]; sy += v[1]; sz += v[2]; sw += v[3];
    }
    int mi = c >> 2, ni = c & 3;
    int grow = bm + wm + mi * 16 + quad * 4;
    int gcol = bn + wn + ni * 16 + r;
    C[(size_t)(grow + 0) * N + gcol] = sx;
    C[(size_t)(grow + 1) * N + gcol] = sy;
    C[(size_t)(grow + 2) * N + gcol] = sz;
    C[(size_t)(grow + 3) * N + gcol] = sw;
  }
}

extern "C" void kernel_launch(void* const* d_in, const int* in_sizes, int n_in,
                              void* d_out, int out_size, void* d_ws, size_t ws_size,
                              hipStream_t stream) {
  const float* x = (const float*)d_in[0];
  const int* wp = (const int*)d_in[1];
  const float* wscale = (const float*)d_in[2];
  const int* wzero = (const int*)d_in[3];
  float* out = (float*)d_out;

  int M = in_sizes[0] / IN_F;  // 1024
  int tiles = (M / BM) * (OUT_F / BN);  // 256

  size_t wb_bytes = (size_t)OUT_F * IN_F * 2;   // 33.5 MB
  size_t xb_bytes = (size_t)M * IN_F * 2;       // 8.4 MB
  size_t slab_set = (size_t)M * OUT_F * 4;      // 16.8 MB per split

  // Pick largest SK in {4,2,1} whose footprint fits ws_size (SK=1 = 58.8 MB,
  // known to fit from round 1). Deterministic across calls: same every launch.
  int SK = 4;
  while (SK > 1 && wb_bytes + xb_bytes + (size_t)SK * slab_set + tiles * 4 > ws_size)
    SK >>= 1;

  __hip_bfloat16* Wb = (__hip_bfloat16*)d_ws;
  __hip_bfloat16* Xb = (__hip_bfloat16*)((char*)d_ws + wb_bytes);
  float* Parts = (float*)((char*)d_ws + wb_bytes + xb_bytes);
  unsigned* cnt = (unsigned*)((char*)d_ws + wb_bytes + xb_bytes + (size_t)SK * slab_set);

  hipMemsetAsync(cnt, 0, (size_t)tiles * 4, stream);

  prep_kernel<<<DQ_BLOCKS + CV_BLOCKS, 256, 0, stream>>>(wp, wscale, wzero, Wb, x, Xb);

  dim3 grid(OUT_F / BN, M / BM, SK);
  gemm_bt<<<grid, 256, 0, stream>>>(Xb, Wb, out, Parts, cnt, M, OUT_F, IN_F);
}

// Round 5
// 153.323 us; speedup vs baseline: 2.1050x; 2.1050x over previous
//
#include <hip/hip_runtime.h>
#include <hip/hip_bf16.h>
#include <stdint.h>

#define IN_F 4096
#define OUT_F 4096
#define NG 32

typedef __attribute__((ext_vector_type(8))) short short8;
typedef __attribute__((ext_vector_type(4))) float floatx4;

#define DQ_BLOCKS 8192   // dequant: 2097152 int32 / 256
#define CV_BLOCKS 2048   // convert: 1024*4096 floats / 8 / 256

// Fused prep: blocks [0, DQ_BLOCKS) dequant W, [DQ_BLOCKS, +CV_BLOCKS) convert x.
__global__ __launch_bounds__(256) void prep_kernel(
    const int* __restrict__ wp, const float* __restrict__ scale,
    const int* __restrict__ zero, __hip_bfloat16* __restrict__ Wb,
    const float* __restrict__ x, __hip_bfloat16* __restrict__ xb) {
  int b = blockIdx.x;
  if (b < DQ_BLOCKS) {
    int p = b * 256 + threadIdx.x;                  // 0 .. 2097151
    int row = p >> 9;                               // 512 int32 per output row
    int g = (p >> 4) & 31;                          // 16 int32 per 128-group
    float s = scale[row * NG + g];
    float zs = (float)zero[row * NG + g] * s;
    unsigned v = (unsigned)wp[p];
    union { __hip_bfloat16 h[8]; uint4 u4; } o;
#pragma unroll
    for (int i = 0; i < 8; ++i) {
      int q = (int)((v >> (4 * i)) & 15u);
      q -= (q >= 8) ? 16 : 0;                       // signed 4-bit
      o.h[i] = __float2bfloat16((float)q * s - zs); // (q - zero) * scale
    }
    *(uint4*)(Wb + (size_t)p * 8) = o.u4;
  } else {
    int i = (b - DQ_BLOCKS) * 256 + threadIdx.x;    // 8 floats per thread
    float4 v0 = ((const float4*)x)[i * 2];
    float4 v1 = ((const float4*)x)[i * 2 + 1];
    union { __hip_bfloat16 h[8]; uint4 u4; } o;
    o.h[0] = __float2bfloat16(v0.x); o.h[1] = __float2bfloat16(v0.y);
    o.h[2] = __float2bfloat16(v0.z); o.h[3] = __float2bfloat16(v0.w);
    o.h[4] = __float2bfloat16(v1.x); o.h[5] = __float2bfloat16(v1.y);
    o.h[6] = __float2bfloat16(v1.z); o.h[7] = __float2bfloat16(v1.w);
    ((uint4*)xb)[i] = o.u4;
  }
}

// Partials[z][m][n] = sum_{k in chunk z} A[m][k] * Bt[n][k].
// 128x128 tile / 256 threads (4 waves, each 64x64 = acc[4][4] of 16x16x32 bf16).
// Plain stores only — no atomics, no fences (rounds 3/4 showed device-scope
// coherence ops in the epilogue cost >> a separate reduce dispatch).
#define BM 128
#define BN 128
#define BK 64
#define SPLITK 4

__global__ __launch_bounds__(256) void gemm_bt(
    const __hip_bfloat16* __restrict__ A, const __hip_bfloat16* __restrict__ Bt,
    float* __restrict__ Parts, int M, int N, int K) {
  __shared__ short Alds[BM * BK];   // [row][k], stride 64, unpadded (global_load_lds)
  __shared__ short Blds[BN * BK];

  int t = threadIdx.x;
  int wave = t >> 6, lane = t & 63;
  int wm = (wave >> 1) * 64, wn = (wave & 1) * 64;
  int r = lane & 15, quad = lane >> 4;
  int bm = blockIdx.y * BM, bn = blockIdx.x * BN;
  int kz = blockIdx.z * (K / SPLITK);
  int kend = kz + K / SPLITK;

  floatx4 acc[4][4] = {};

  const __hip_bfloat16* Ag = A + (size_t)bm * K;
  const __hip_bfloat16* Bg = Bt + (size_t)bn * K;

  for (int k0 = kz; k0 < kend; k0 += BK) {
    __syncthreads();  // previous compute done before overwriting LDS
#pragma unroll
    for (int j = 0; j < 4; ++j) {
      int c = t + 256 * j;            // 16B chunk id, 8 chunks per row
      int row = c >> 3, kc = c & 7;
      const __hip_bfloat16* ga = Ag + (size_t)row * K + k0 + kc * 8;
      const __hip_bfloat16* gb = Bg + (size_t)row * K + k0 + kc * 8;
      __builtin_amdgcn_global_load_lds(
          (const __attribute__((address_space(1))) void*)ga,
          (__attribute__((address_space(3))) void*)(&Alds[c * 8]), 16, 0, 0);
      __builtin_amdgcn_global_load_lds(
          (const __attribute__((address_space(1))) void*)gb,
          (__attribute__((address_space(3))) void*)(&Blds[c * 8]), 16, 0, 0);
    }
    __syncthreads();  // implies vmcnt(0): staged data visible

#pragma unroll
    for (int ks = 0; ks < 2; ++ks) {
      int kk = ks * 32;
      short8 af[4], bf[4];
#pragma unroll
      for (int mi = 0; mi < 4; ++mi)
        af[mi] = *(const short8*)&Alds[(wm + mi * 16 + r) * BK + kk + quad * 8];
#pragma unroll
      for (int ni = 0; ni < 4; ++ni)
        bf[ni] = *(const short8*)&Blds[(wn + ni * 16 + r) * BK + kk + quad * 8];
#pragma unroll
      for (int mi = 0; mi < 4; ++mi)
#pragma unroll
        for (int ni = 0; ni < 4; ++ni)
          acc[mi][ni] = __builtin_amdgcn_mfma_f32_16x16x32_bf16(
              af[mi], bf[ni], acc[mi][ni], 0, 0, 0);
    }
  }

  // Epilogue: plain stores, C layout (col = lane&15, row = quad*4 + reg).
  float* Cz = Parts + (size_t)blockIdx.z * M * N;
#pragma unroll
  for (int mi = 0; mi < 4; ++mi) {
#pragma unroll
    for (int ni = 0; ni < 4; ++ni) {
#pragma unroll
      for (int i = 0; i < 4; ++i) {
        int grow = bm + wm + mi * 16 + quad * 4 + i;
        int gcol = bn + wn + ni * 16 + r;
        Cz[(size_t)grow * N + gcol] = acc[mi][ni][i];
      }
    }
  }
}

// out = p0 + p1 + p2 + p3, fully coalesced float4.
__global__ __launch_bounds__(256) void reduce_kernel(
    float* __restrict__ out, const float* __restrict__ parts, int mn) {
  int i = blockIdx.x * 256 + threadIdx.x;
  const float4* p = (const float4*)parts;
  int stride = mn / 4;
  float4 a = p[i];
  float4 b = p[i + stride];
  float4 c = p[i + 2 * stride];
  float4 d = p[i + 3 * stride];
  a.x += b.x + c.x + d.x;
  a.y += b.y + c.y + d.y;
  a.z += b.z + c.z + d.z;
  a.w += b.w + c.w + d.w;
  ((float4*)out)[i] = a;
}

extern "C" void kernel_launch(void* const* d_in, const int* in_sizes, int n_in,
                              void* d_out, int out_size, void* d_ws, size_t ws_size,
                              hipStream_t stream) {
  const float* x = (const float*)d_in[0];
  const int* wp = (const int*)d_in[1];
  const float* wscale = (const float*)d_in[2];
  const int* wzero = (const int*)d_in[3];
  float* out = (float*)d_out;

  int M = in_sizes[0] / IN_F;  // 1024

  size_t wb_bytes = (size_t)OUT_F * IN_F * 2;   // 33.5 MB
  size_t xb_bytes = (size_t)M * IN_F * 2;       // 8.4 MB

  __hip_bfloat16* Wb = (__hip_bfloat16*)d_ws;
  __hip_bfloat16* Xb = (__hip_bfloat16*)((char*)d_ws + wb_bytes);
  float* Parts = (float*)((char*)d_ws + wb_bytes + xb_bytes);  // 4 x 16.8 MB

  prep_kernel<<<DQ_BLOCKS + CV_BLOCKS, 256, 0, stream>>>(wp, wscale, wzero, Wb, x, Xb);

  dim3 grid(OUT_F / BN, M / BM, SPLITK);
  gemm_bt<<<grid, 256, 0, stream>>>(Xb, Wb, Parts, M, OUT_F, IN_F);

  int mn = M * OUT_F;
  reduce_kernel<<<(mn / 4) / 256, 256, 0, stream>>>(out, Parts, mn);
}

// Round 6
// 147.658 us; speedup vs baseline: 2.1858x; 1.0384x over previous
//
#include <hip/hip_runtime.h>
#include <hip/hip_bf16.h>
#include <stdint.h>

#define IN_F 4096
#define OUT_F 4096
#define NG 32

typedef __attribute__((ext_vector_type(8))) short short8;
typedef __attribute__((ext_vector_type(4))) float floatx4;

// x fp32 -> bf16, 8 floats/thread.
__global__ __launch_bounds__(256) void convert_kernel(
    const float* __restrict__ x, __hip_bfloat16* __restrict__ xb) {
  int i = blockIdx.x * 256 + threadIdx.x;
  float4 v0 = ((const float4*)x)[i * 2];
  float4 v1 = ((const float4*)x)[i * 2 + 1];
  union { __hip_bfloat16 h[8]; uint4 u4; } o;
  o.h[0] = __float2bfloat16(v0.x); o.h[1] = __float2bfloat16(v0.y);
  o.h[2] = __float2bfloat16(v0.z); o.h[3] = __float2bfloat16(v0.w);
  o.h[4] = __float2bfloat16(v1.x); o.h[5] = __float2bfloat16(v1.y);
  o.h[6] = __float2bfloat16(v1.z); o.h[7] = __float2bfloat16(v1.w);
  ((uint4*)xb)[i] = o.u4;
}

// Fused int4-dequant GEMM: C[m][n] = sum_k A[m][k] * W[n][k],
// W dequantized from packed nibbles IN the k-loop (B-tile staged as 4 KB
// packed instead of 16 KB bf16 -> staging drops below the MFMA floor).
// 128x128 tile / 256 threads (4 waves, 64x64 each). Split-K=2:
// z=0 -> C0 (d_out), z=1 -> C1 (ws partial); reduce adds. Plain stores only.
#define BM 128
#define BN 128
#define BK 64
#define SPLITK 2
#define BSTRIDE 68   // B LDS row stride in shorts: +4 pad -> 4-way instead of 16-way

__global__ __launch_bounds__(256) void gemm_bt(
    const __hip_bfloat16* __restrict__ A, const uint32_t* __restrict__ wp,
    const float* __restrict__ scale, const int* __restrict__ zero,
    float* __restrict__ C0, float* __restrict__ C1, int M, int N, int K) {
  __shared__ short Alds[BM * BK];        // [row][64], unpadded (global_load_lds)
  __shared__ short Blds[BN * BSTRIDE];   // [row][68], padded (ds_write path)

  int t = threadIdx.x;
  int wave = t >> 6, lane = t & 63;
  int wm = (wave >> 1) * 64, wn = (wave & 1) * 64;
  int r = lane & 15, quad = lane >> 4;
  int bm = blockIdx.y * BM, bn = blockIdx.x * BN;
  int kz = blockIdx.z * (K / SPLITK);
  int kend = kz + K / SPLITK;

  // B-dequant assignment: 2 threads per row; each covers a 32-elem k-span.
  int row2 = t >> 1, half = t & 1;
  int wrow = bn + row2;
  const uint4* wrow4 = (const uint4*)(wp + (size_t)wrow * (IN_F / 8));  // 64 uint4/row

  floatx4 acc[4][4] = {};

  const __hip_bfloat16* Ag = A + (size_t)bm * K;

  // Prefetch first packed B chunk + first group's scale/zero.
  uint4 bp = wrow4[(kz >> 5) + half];        // uint4 index: k0/32 + half
  float s = scale[wrow * NG + (kz >> 7)];
  float zs = (float)zero[wrow * NG + (kz >> 7)] * s;

  for (int k0 = kz; k0 < kend; k0 += BK) {
    __syncthreads();  // previous MFMA-phase LDS reads done
    // --- A staging: global -> LDS direct, 4x 16B chunks per thread ---
#pragma unroll
    for (int j = 0; j < 4; ++j) {
      int c = t + 256 * j;            // 16B chunk id in [0,1024)
      int rowA = c >> 3, kc = c & 7;
      __builtin_amdgcn_global_load_lds(
          (const __attribute__((address_space(1))) void*)(Ag + (size_t)rowA * K + k0 + kc * 8),
          (__attribute__((address_space(3))) void*)(&Alds[c * 8]), 16, 0, 0);
    }
    // --- B dequant: 32 nibbles -> bf16 -> LDS (4x ds_write_b128) ---
    int kb = half * 32;               // this thread's k-offset within the tile
#pragma unroll
    for (int e = 0; e < 4; ++e) {
      uint32_t w = (&bp.x)[e];        // 8 nibbles, k ascending
      union { __hip_bfloat16 h[8]; uint4 u4; } o;
#pragma unroll
      for (int i = 0; i < 8; ++i) {
        int q = ((int)(w << (28 - 4 * i))) >> 28;   // sign-extended nibble (bfe_i32)
        o.h[i] = __float2bfloat16((float)q * s - zs); // (q - zero)*scale
      }
      *(uint4*)&Blds[row2 * BSTRIDE + kb + e * 8] = o.u4;
    }
    // --- Prefetch next k-iter's packed B + (maybe) next group's scale/zero ---
    int kn = k0 + BK;
    if (kn < kend) {
      bp = wrow4[(kn >> 5) + half];
      if ((kn & 127) == 0) {          // new 128-group (wave-uniform branch)
        s = scale[wrow * NG + (kn >> 7)];
        zs = (float)zero[wrow * NG + (kn >> 7)] * s;
      }
    }
    __syncthreads();  // drains vmcnt (A-lds) + lgkm (B ds_write): tiles visible

    // --- MFMA phase ---
#pragma unroll
    for (int ks = 0; ks < 2; ++ks) {
      int kk = ks * 32;
      short8 af[4], bf[4];
#pragma unroll
      for (int mi = 0; mi < 4; ++mi)
        af[mi] = *(const short8*)&Alds[(wm + mi * 16 + r) * BK + kk + quad * 8];
#pragma unroll
      for (int ni = 0; ni < 4; ++ni)
        bf[ni] = *(const short8*)&Blds[(wn + ni * 16 + r) * BSTRIDE + kk + quad * 8];
#pragma unroll
      for (int mi = 0; mi < 4; ++mi)
#pragma unroll
        for (int ni = 0; ni < 4; ++ni)
          acc[mi][ni] = __builtin_amdgcn_mfma_f32_16x16x32_bf16(
              af[mi], bf[ni], acc[mi][ni], 0, 0, 0);
    }
  }

  // Epilogue: plain stores (no atomics/fences — rounds 3/4 lesson).
  // C/D layout: col = lane&15, row = quad*4 + reg.
  float* Cz = (blockIdx.z == 0) ? C0 : C1;
#pragma unroll
  for (int mi = 0; mi < 4; ++mi) {
#pragma unroll
    for (int ni = 0; ni < 4; ++ni) {
#pragma unroll
      for (int i = 0; i < 4; ++i) {
        int grow = bm + wm + mi * 16 + quad * 4 + i;
        int gcol = bn + wn + ni * 16 + r;
        Cz[(size_t)grow * N + gcol] = acc[mi][ni][i];
      }
    }
  }
}

// out += part, fully coalesced float4.
__global__ __launch_bounds__(256) void reduce_kernel(
    float* __restrict__ out, const float* __restrict__ part) {
  int i = blockIdx.x * 256 + threadIdx.x;
  float4 a = ((const float4*)out)[i];
  float4 b = ((const float4*)part)[i];
  a.x += b.x; a.y += b.y; a.z += b.z; a.w += b.w;
  ((float4*)out)[i] = a;
}

extern "C" void kernel_launch(void* const* d_in, const int* in_sizes, int n_in,
                              void* d_out, int out_size, void* d_ws, size_t ws_size,
                              hipStream_t stream) {
  const float* x = (const float*)d_in[0];
  const uint32_t* wp = (const uint32_t*)d_in[1];
  const float* wscale = (const float*)d_in[2];
  const int* wzero = (const int*)d_in[3];
  float* out = (float*)d_out;

  int M = in_sizes[0] / IN_F;  // 1024

  __hip_bfloat16* Xb = (__hip_bfloat16*)d_ws;                       // 8.4 MB
  float* Cpart = (float*)((char*)d_ws + (size_t)M * IN_F * 2);      // 16.8 MB

  convert_kernel<<<(M * IN_F / 8) / 256, 256, 0, stream>>>(x, Xb);

  dim3 grid(OUT_F / BN, M / BM, SPLITK);
  gemm_bt<<<grid, 256, 0, stream>>>(Xb, wp, wscale, wzero, out, Cpart, M, OUT_F, IN_F);

  reduce_kernel<<<(M * OUT_F / 4) / 256, 256, 0, stream>>>(out, Cpart);
}